// Round 19
// baseline (55.230 us; speedup 1.0000x reference)
//
#include <hip/hip_runtime.h>

#define BB 4
#define NN 8192
#define MM 2048
#define CC 64
#define KK 16
#define QB 8   // queries per block (v9)

// ---------------------------------------------------------------------------
// VERIFIED (round 7, absmax=0): reference rounding = XLA-CPU FPOpFusion::Fast:
//   qq  = fma(qz,qz, fma(qy,qy, qx*qx))
//   pp  = fma(pz,pz, fma(py,py, px*px))
//   dot = fma(qz,pz, fma(qy,py, qx*px))
//   d   = (qq - 2*dot) + pp
// DO NOT CHANGE. They decide the FINAL ordering (Phase C).
// ---------------------------------------------------------------------------
__device__ __forceinline__ float sq3(float x, float y, float z) {
    return __fmaf_rn(z, z, __fmaf_rn(y, y, __fmul_rn(x, x)));
}
__device__ __forceinline__ float dist32(float qx, float qy, float qz, float qq,
                                        float px, float py, float pz, float pp) {
    float dot = __fmaf_rn(qz, pz, __fmaf_rn(qy, py, __fmul_rn(qx, px)));
    return __fadd_rn(__fsub_rn(qq, __fmul_rn(2.0f, dot)), pp);
}
// Surrogate for SELECTION only: nq = -2*q; s = fma(nqz,pz, fma(nqy,py,
// fma(nqx,px, pp))). |(s+qq)-d| <= ~1e-5; SLACK=1e-3 keeps the candidate set
// {s <= tau} a superset of the true top-16. Final order from dist32 (Phase C).
__device__ __forceinline__ float surr(float nqx, float nqy, float nqz,
                                      float px, float py, float pz, float pp) {
    return __fmaf_rn(nqz, pz, __fmaf_rn(nqy, py, __fmaf_rn(nqx, px, pp)));
}
#define SLACK 1e-3f

// ---------------------------------------------------------------------------
// Prep kernel (v8): float4 both sides; transpose feats [B,C,N]->[B,N,C] and
// precompute pp[b][n] (same intrinsic chain as inline -> identical bits).
// ---------------------------------------------------------------------------
__global__ __launch_bounds__(256) void prep_feats_pp(const float* __restrict__ f,
                                                     const float* __restrict__ points,
                                                     float* __restrict__ ft,
                                                     float* __restrict__ pp) {
    __shared__ float tile[64][65];
    const int b  = blockIdx.y;
    const int n0 = blockIdx.x * 64;
    const int t  = threadIdx.x;
    const float* src = f + (size_t)b * CC * NN;
    float* dst       = ft + (size_t)b * NN * CC;
#pragma unroll
    for (int it = 0; it < 4; ++it) {
        const int c  = (t >> 4) + it * 16;
        const int n4 = (t & 15) * 4;
        const float4 v = *(const float4*)(src + (size_t)c * NN + n0 + n4);
        tile[c][n4 + 0] = v.x; tile[c][n4 + 1] = v.y;
        tile[c][n4 + 2] = v.z; tile[c][n4 + 3] = v.w;
    }
    if (t < 64) {
        const float* pb = points + (size_t)b * 3 * NN;
        const int n = n0 + t;
        pp[(size_t)b * NN + n] = sq3(pb[n], pb[NN + n], pb[2 * NN + n]);
    }
    __syncthreads();
#pragma unroll
    for (int it = 0; it < 4; ++it) {
        const int n  = (t >> 4) + it * 16;
        const int c4 = (t & 15) * 4;
        const float4 v = make_float4(tile[c4 + 0][n], tile[c4 + 1][n],
                                     tile[c4 + 2][n], tile[c4 + 3][n]);
        *(float4*)(dst + (size_t)(n0 + n) * CC + c4) = v;
    }
}

// ---------------------------------------------------------------------------
// Kernel 2 (v9): Q=8 queries/block (was 4). Each loaded point now serves 8
// queries -> L2 point traffic halves; total VALU/sort work unchanged.
// 1024 blocks, 4 waves each on a disjoint 2048-pt range. lb(256,4): grid
// caps at 4 blocks/CU anyway; lifting the VGPR cap avoids spills at Q=8.
// ---------------------------------------------------------------------------
template <bool PPQ>
__global__ __launch_bounds__(256, 4) void knn_group9(const float* __restrict__ points,
                                                     const float* __restrict__ newp,
                                                     const float* __restrict__ feat,
                                                     const float* __restrict__ ppw,
                                                     float* __restrict__ out) {
    const int wave = threadIdx.x >> 6;
    const int lane = threadIdx.x & 63;
    const int qbase = blockIdx.x * QB;
    const int b  = qbase / MM;
    const int m0 = qbase % MM;

    const float* px_ = points + (size_t)b * 3 * NN;
    const float* py_ = px_ + NN;
    const float* pz_ = py_ + NN;
    const float* q_  = newp + (size_t)b * 3 * MM;
    const float* ppb = PPQ ? (ppw + (size_t)b * NN) : nullptr;

    float nqx[QB], nqy[QB], nqz[QB];
#pragma unroll
    for (int q = 0; q < QB; ++q) {
        nqx[q] = __fmul_rn(-2.0f, q_[m0 + q]);
        nqy[q] = __fmul_rn(-2.0f, q_[MM + m0 + q]);
        nqz[q] = __fmul_rn(-2.0f, q_[2 * MM + m0 + q]);
    }

    const float INF = __int_as_float(0x7f800000);
    const int base = wave * (NN / 4);

    __shared__ union SM {
        struct { float top[QB][4][16]; float tau[QB]; int cnt[QB]; int idx[QB][64]; } a;
        float g[3 + CC][129];   // stride 129: scatter 2-way, read stride-1
    } sm;
    __shared__ int s_win[QB][16];

    // ---- Phase A: per-lane min surrogate over 32 points, 8 queries ----
    float m1[QB];
#pragma unroll
    for (int q = 0; q < QB; ++q) m1[q] = INF;
#pragma unroll 4
    for (int j4 = 0; j4 < 8; ++j4) {
        const int ib = base + j4 * 256 + lane * 4;
        const float4 vx = *(const float4*)(px_ + ib);
        const float4 vy = *(const float4*)(py_ + ib);
        const float4 vz = *(const float4*)(pz_ + ib);
        float4 vp;
        if (PPQ) vp = *(const float4*)(ppb + ib);
        else vp = make_float4(sq3(vx.x, vy.x, vz.x), sq3(vx.y, vy.y, vz.y),
                              sq3(vx.z, vy.z, vz.z), sq3(vx.w, vy.w, vz.w));
        const float pxa[4] = {vx.x, vx.y, vx.z, vx.w};
        const float pya[4] = {vy.x, vy.y, vy.z, vy.w};
        const float pza[4] = {vz.x, vz.y, vz.z, vz.w};
        const float ppa[4] = {vp.x, vp.y, vp.z, vp.w};
#pragma unroll
        for (int e = 0; e < 4; e += 2) {
#pragma unroll
            for (int q = 0; q < QB; ++q) {
                const float s0 = surr(nqx[q], nqy[q], nqz[q],
                                      pxa[e], pya[e], pza[e], ppa[e]);
                const float s1 = surr(nqx[q], nqy[q], nqz[q],
                                      pxa[e + 1], pya[e + 1], pza[e + 1], ppa[e + 1]);
                m1[q] = fminf(fminf(m1[q], s0), s1);   // -> v_min3_f32
            }
        }
    }

    // ---- 8 bitonic-64 sorts, two 4-interleaved batches ----
#pragma unroll
    for (int g4 = 0; g4 < 2; ++g4) {
        float v0 = m1[g4 * 4 + 0], v1 = m1[g4 * 4 + 1];
        float v2 = m1[g4 * 4 + 2], v3 = m1[g4 * 4 + 3];
#pragma unroll
        for (int k = 2; k <= 64; k <<= 1) {
#pragma unroll
            for (int j = k >> 1; j > 0; j >>= 1) {
                const bool keepMin = ((lane & j) == 0) == ((lane & k) == 0);
                const float p0 = __shfl_xor(v0, j, 64);
                const float p1 = __shfl_xor(v1, j, 64);
                const float p2 = __shfl_xor(v2, j, 64);
                const float p3 = __shfl_xor(v3, j, 64);
                v0 = keepMin ? fminf(v0, p0) : fmaxf(v0, p0);
                v1 = keepMin ? fminf(v1, p1) : fmaxf(v1, p1);
                v2 = keepMin ? fminf(v2, p2) : fmaxf(v2, p2);
                v3 = keepMin ? fminf(v3, p3) : fmaxf(v3, p3);
            }
        }
        if (lane < 16) {
            sm.a.top[g4 * 4 + 0][wave][lane] = v0;
            sm.a.top[g4 * 4 + 1][wave][lane] = v1;
            sm.a.top[g4 * 4 + 2][wave][lane] = v2;
            sm.a.top[g4 * 4 + 3][wave][lane] = v3;
        }
    }
    if (threadIdx.x < QB) sm.a.cnt[threadIdx.x] = 0;
    __syncthreads();

    // ---- tau[q]: wave handles q = wave and wave+4 (exact 16th of 256) ----
#pragma unroll
    for (int t = 0; t < 2; ++t) {
        const int q = wave + t * 4;
        float v = sm.a.top[q][lane >> 4][lane & 15];
#pragma unroll
        for (int k = 2; k <= 64; k <<= 1) {
#pragma unroll
            for (int j = k >> 1; j > 0; j >>= 1) {
                const float pv = __shfl_xor(v, j, 64);
                const bool keepMin = ((lane & j) == 0) == ((lane & k) == 0);
                v = keepMin ? fminf(v, pv) : fmaxf(v, pv);
            }
        }
        if (lane == 15) sm.a.tau[q] = v + SLACK;
    }
    __syncthreads();
    float tauS[QB];
#pragma unroll
    for (int q = 0; q < QB; ++q) tauS[q] = sm.a.tau[q];

    // ---- Phase B: rescan; lanes provably without candidates skip ----
    bool anyc = false;
#pragma unroll
    for (int q = 0; q < QB; ++q) anyc |= (m1[q] <= tauS[q]);
    if (anyc) {
#pragma unroll 4
        for (int j4 = 0; j4 < 8; ++j4) {
            const int ib = base + j4 * 256 + lane * 4;
            const float4 vx = *(const float4*)(px_ + ib);
            const float4 vy = *(const float4*)(py_ + ib);
            const float4 vz = *(const float4*)(pz_ + ib);
            float4 vp;
            if (PPQ) vp = *(const float4*)(ppb + ib);
            else vp = make_float4(sq3(vx.x, vy.x, vz.x), sq3(vx.y, vy.y, vz.y),
                                  sq3(vx.z, vy.z, vz.z), sq3(vx.w, vy.w, vz.w));
            const float pxa[4] = {vx.x, vx.y, vx.z, vx.w};
            const float pya[4] = {vy.x, vy.y, vy.z, vy.w};
            const float pza[4] = {vz.x, vz.y, vz.z, vz.w};
            const float ppa[4] = {vp.x, vp.y, vp.z, vp.w};
#pragma unroll
            for (int e = 0; e < 4; ++e) {
#pragma unroll
                for (int q = 0; q < QB; ++q) {
                    const float s = surr(nqx[q], nqy[q], nqz[q],
                                         pxa[e], pya[e], pza[e], ppa[e]);
                    if (s <= tauS[q]) {
                        const int pos = atomicAdd(&sm.a.cnt[q], 1);
                        if (pos < 64) sm.a.idx[q][pos] = ib + e;
                    }
                }
            }
        }
    }
    __syncthreads();

    // ---- Phase C: wave handles q = wave, wave+4; exact dist32 + sort ----
#pragma unroll
    for (int t = 0; t < 2; ++t) {
        const int q = wave + t * 4;
        const int m = m0 + q;
        const float qx = q_[m], qy = q_[MM + m], qz = q_[2 * MM + m];
        const float qq = sq3(qx, qy, qz);
        const int cnt = min(sm.a.cnt[q], 64);
        float d = INF;
        int idx = 0x7fffffff;
        if (lane < cnt) {
            idx = sm.a.idx[q][lane];
            const float px = px_[idx], py = py_[idx], pz = pz_[idx];
            d = dist32(qx, qy, qz, qq, px, py, pz, sq3(px, py, pz));
        }
#pragma unroll
        for (int k = 2; k <= 64; k <<= 1) {
#pragma unroll
            for (int j = k >> 1; j > 0; j >>= 1) {
                const float pd = __shfl_xor(d, j, 64);
                const int   pi = __shfl_xor(idx, j, 64);
                const bool keepMin = ((lane & j) == 0) == ((lane & k) == 0);
                const bool pLess = (pd < d) || (pd == d && pi < idx);
                if (keepMin ? pLess : !pLess) { d = pd; idx = pi; }
            }
        }
        if (lane < KK) s_win[q][lane] = idx;
    }
    __syncthreads();   // s_win ready; sort buffers dead -> sm.g reuse OK

    const size_t chs = (size_t)MM * KK;
    float* obase = out + (size_t)b * (3 + CC) * chs + (size_t)m0 * KK;

    if (PPQ) {
        // ---- stage 1: coalesced gather into LDS transpose buffer ----
        const float* ftb = feat + (size_t)b * NN * CC;
#pragma unroll
        for (int it = 0; it < 8; ++it) {
            const int nb = wave * 32 + it * 4 + (lane >> 4);  // 0..127
            const int cg = lane & 15;
            const int idx = s_win[nb >> 4][nb & 15];
            const float4 v = *(const float4*)(ftb + (size_t)idx * CC + cg * 4);
            sm.g[3 + cg * 4 + 0][nb] = v.x;
            sm.g[3 + cg * 4 + 1][nb] = v.y;
            sm.g[3 + cg * 4 + 2][nb] = v.z;
            sm.g[3 + cg * 4 + 3][nb] = v.w;
        }
        if (threadIdx.x < 128) {
            const int nb = threadIdx.x;
            const int q2 = nb >> 4;
            const int m  = m0 + q2;
            const int idx = s_win[q2][nb & 15];
            sm.g[0][nb] = __fsub_rn(px_[idx], q_[m]);
            sm.g[1][nb] = __fsub_rn(py_[idx], q_[MM + m]);
            sm.g[2][nb] = __fsub_rn(pz_[idx], q_[2 * MM + m]);
        }
        __syncthreads();
        // ---- stage 2: stride-1 LDS reads + coalesced 256B stores ----
#pragma unroll
        for (int t = 0; t < 17; ++t) {
            const int c = wave + t * 4;
            if (c < 3 + CC) {
                obase[(size_t)c * chs + lane]      = sm.g[c][lane];
                obase[(size_t)c * chs + 64 + lane] = sm.g[c][64 + lane];
            }
        }
    } else {
        // Fallback (no ws): strided gather, thread<128 handles one neighbor.
        if (threadIdx.x < 128) {
            const int nb = threadIdx.x;
            const int q2 = nb >> 4;
            const int m  = m0 + q2;
            const int idx = s_win[q2][nb & 15];
            float* ob = obase + (size_t)(nb >> 4) * KK + (nb & 15);
            ob[0]           = __fsub_rn(px_[idx], q_[m]);
            ob[chs]         = __fsub_rn(py_[idx], q_[MM + m]);
            ob[2 * chs]     = __fsub_rn(pz_[idx], q_[2 * MM + m]);
            const float* fr = feat + (size_t)b * CC * NN + idx;
#pragma unroll 8
            for (int c = 0; c < CC; ++c)
                ob[(size_t)(3 + c) * chs] = fr[(size_t)c * NN];
        }
    }
}

extern "C" void kernel_launch(void* const* d_in, const int* in_sizes, int n_in,
                              void* d_out, int out_size, void* d_ws, size_t ws_size,
                              hipStream_t stream) {
    const float* points = (const float*)d_in[0];
    const float* newp   = (const float*)d_in[1];
    const float* feats  = (const float*)d_in[2];
    float* out = (float*)d_out;

    const size_t ftElems = (size_t)BB * NN * CC;
    const size_t needBytes = (ftElems + (size_t)BB * NN) * sizeof(float);
    if (ws_size >= needBytes) {
        float* ft  = (float*)d_ws;
        float* ppw = ft + ftElems;
        prep_feats_pp<<<dim3(NN / 64, BB), 256, 0, stream>>>(feats, points, ft, ppw);
        knn_group9<true><<<(BB * MM) / QB, 256, 0, stream>>>(points, newp, ft, ppw, out);
    } else {
        knn_group9<false><<<(BB * MM) / QB, 256, 0, stream>>>(points, newp, feats, nullptr, out);
    }
}

// Round 20
// 48.092 us; speedup vs baseline: 1.1484x; 1.1484x over previous
//
#include <hip/hip_runtime.h>

#define BB 4
#define NN 8192
#define MM 2048
#define CC 64
#define KK 16

// ---------------------------------------------------------------------------
// VERIFIED (round 7, absmax=0): reference rounding = XLA-CPU FPOpFusion::Fast:
//   qq  = fma(qz,qz, fma(qy,qy, qx*qx))
//   pp  = fma(pz,pz, fma(py,py, px*px))
//   dot = fma(qz,pz, fma(qy,py, qx*px))
//   d   = (qq - 2*dot) + pp
// DO NOT CHANGE. They decide the FINAL ordering (Phase C).
// ---------------------------------------------------------------------------
__device__ __forceinline__ float sq3(float x, float y, float z) {
    return __fmaf_rn(z, z, __fmaf_rn(y, y, __fmul_rn(x, x)));
}
__device__ __forceinline__ float dist32(float qx, float qy, float qz, float qq,
                                        float px, float py, float pz, float pp) {
    float dot = __fmaf_rn(qz, pz, __fmaf_rn(qy, py, __fmul_rn(qx, px)));
    return __fadd_rn(__fsub_rn(qq, __fmul_rn(2.0f, dot)), pp);
}
// Surrogate for SELECTION only: nq = -2*q; s = fma(nqz,pz, fma(nqy,py,
// fma(nqx,px, pp))). |(s+qq)-d| <= ~1e-5; SLACK=1e-3 keeps the candidate set
// {s <= tau} a superset of the true top-16. Final order from dist32 (Phase C).
__device__ __forceinline__ float surr(float nqx, float nqy, float nqz,
                                      float px, float py, float pz, float pp) {
    return __fmaf_rn(nqz, pz, __fmaf_rn(nqy, py, __fmaf_rn(nqx, px, pp)));
}
#define SLACK 1e-3f

// ---------------------------------------------------------------------------
// Prep kernel (v8: float4 both sides): transpose features [B,C,N] -> [B,N,C]
// + precompute pp[b][n] (same intrinsic chain as inline -> identical bits).
// ---------------------------------------------------------------------------
__global__ __launch_bounds__(256) void prep_feats_pp(const float* __restrict__ f,
                                                     const float* __restrict__ points,
                                                     float* __restrict__ ft,
                                                     float* __restrict__ pp) {
    __shared__ float tile[64][65];
    const int b  = blockIdx.y;
    const int n0 = blockIdx.x * 64;
    const int t  = threadIdx.x;
    const float* src = f + (size_t)b * CC * NN;
    float* dst       = ft + (size_t)b * NN * CC;
    // load: thread t -> channel c=(t>>4)+16*it, 4 cols n4=(t&15)*4 (coalesced)
#pragma unroll
    for (int it = 0; it < 4; ++it) {
        const int c  = (t >> 4) + it * 16;
        const int n4 = (t & 15) * 4;
        const float4 v = *(const float4*)(src + (size_t)c * NN + n0 + n4);
        tile[c][n4 + 0] = v.x; tile[c][n4 + 1] = v.y;
        tile[c][n4 + 2] = v.z; tile[c][n4 + 3] = v.w;
    }
    if (t < 64) {
        const float* pb = points + (size_t)b * 3 * NN;
        const int n = n0 + t;
        pp[(size_t)b * NN + n] = sq3(pb[n], pb[NN + n], pb[2 * NN + n]);
    }
    __syncthreads();
    // store: thread t -> row n=(t>>4)+16*it, 4 channels c4=(t&15)*4 (coalesced)
#pragma unroll
    for (int it = 0; it < 4; ++it) {
        const int n  = (t >> 4) + it * 16;
        const int c4 = (t & 15) * 4;
        const float4 v = make_float4(tile[c4 + 0][n], tile[c4 + 1][n],
                                     tile[c4 + 2][n], tile[c4 + 3][n]);
        *(float4*)(dst + (size_t)(n0 + n) * CC + c4) = v;
    }
}

// ---------------------------------------------------------------------------
// Kernel 2 (v8 FINAL, best verified 48.2 us total): block = 4 queries,
// 4 waves on disjoint 2048-pt ranges (2048 blocks -> 8 blocks/CU), exact
// tau via per-range top-16 bitonic merge, surrogate scan + exact Phase C,
// per-lane Phase-B skip guard, LDS-transpose write phase.
// ---------------------------------------------------------------------------
template <bool PPQ>
__global__ __launch_bounds__(256, 8) void knn_group8(const float* __restrict__ points,
                                                     const float* __restrict__ newp,
                                                     const float* __restrict__ feat,
                                                     const int fsN, const int fsC,
                                                     const float* __restrict__ ppw,
                                                     float* __restrict__ out) {
    const int wave = threadIdx.x >> 6;
    const int lane = threadIdx.x & 63;
    const int qbase = blockIdx.x * 4;
    const int b  = qbase / MM;
    const int m0 = qbase % MM;

    const float* px_ = points + (size_t)b * 3 * NN;
    const float* py_ = px_ + NN;
    const float* pz_ = py_ + NN;
    const float* q_  = newp + (size_t)b * 3 * MM;
    const float* ppb = PPQ ? (ppw + (size_t)b * NN) : nullptr;

    float nqx[4], nqy[4], nqz[4];
#pragma unroll
    for (int q = 0; q < 4; ++q) {
        nqx[q] = __fmul_rn(-2.0f, q_[m0 + q]);
        nqy[q] = __fmul_rn(-2.0f, q_[MM + m0 + q]);
        nqz[q] = __fmul_rn(-2.0f, q_[2 * MM + m0 + q]);
    }

    const float INF = __int_as_float(0x7f800000);
    const int base = wave * (NN / 4);

    __shared__ union SM {
        struct { float top[4][4][16]; float tau[4]; int cnt[4]; int idx[4][64]; } a;
        float g[67][65];
    } sm;
    __shared__ int s_win[4][16];

    // ---- Phase A: per-lane min surrogate over 32 points (paired mins) ----
    float m1[4] = {INF, INF, INF, INF};
#pragma unroll 4
    for (int j4 = 0; j4 < 8; ++j4) {
        const int ib = base + j4 * 256 + lane * 4;
        const float4 vx = *(const float4*)(px_ + ib);
        const float4 vy = *(const float4*)(py_ + ib);
        const float4 vz = *(const float4*)(pz_ + ib);
        float4 vp;
        if (PPQ) vp = *(const float4*)(ppb + ib);
        else vp = make_float4(sq3(vx.x, vy.x, vz.x), sq3(vx.y, vy.y, vz.y),
                              sq3(vx.z, vy.z, vz.z), sq3(vx.w, vy.w, vz.w));
        const float pxa[4] = {vx.x, vx.y, vx.z, vx.w};
        const float pya[4] = {vy.x, vy.y, vy.z, vy.w};
        const float pza[4] = {vz.x, vz.y, vz.z, vz.w};
        const float ppa[4] = {vp.x, vp.y, vp.z, vp.w};
#pragma unroll
        for (int e = 0; e < 4; e += 2) {
#pragma unroll
            for (int q = 0; q < 4; ++q) {
                const float s0 = surr(nqx[q], nqy[q], nqz[q],
                                      pxa[e], pya[e], pza[e], ppa[e]);
                const float s1 = surr(nqx[q], nqy[q], nqz[q],
                                      pxa[e + 1], pya[e + 1], pza[e + 1], ppa[e + 1]);
                m1[q] = fminf(fminf(m1[q], s0), s1);   // -> v_min3_f32
            }
        }
    }

    // ---- 4 bitonic-64 sorts on copies of m1, interleaved ----
    {
        float v0 = m1[0], v1 = m1[1], v2 = m1[2], v3 = m1[3];
#pragma unroll
        for (int k = 2; k <= 64; k <<= 1) {
#pragma unroll
            for (int j = k >> 1; j > 0; j >>= 1) {
                const bool keepMin = ((lane & j) == 0) == ((lane & k) == 0);
                const float p0 = __shfl_xor(v0, j, 64);
                const float p1 = __shfl_xor(v1, j, 64);
                const float p2 = __shfl_xor(v2, j, 64);
                const float p3 = __shfl_xor(v3, j, 64);
                v0 = keepMin ? fminf(v0, p0) : fmaxf(v0, p0);
                v1 = keepMin ? fminf(v1, p1) : fmaxf(v1, p1);
                v2 = keepMin ? fminf(v2, p2) : fmaxf(v2, p2);
                v3 = keepMin ? fminf(v3, p3) : fmaxf(v3, p3);
            }
        }
        if (lane < 16) {
            sm.a.top[0][wave][lane] = v0;
            sm.a.top[1][wave][lane] = v1;
            sm.a.top[2][wave][lane] = v2;
            sm.a.top[3][wave][lane] = v3;
        }
    }
    if (threadIdx.x < 4) sm.a.cnt[threadIdx.x] = 0;
    __syncthreads();

    // ---- tau[q]: wave q merges 4 sorted-16 heads -> exact 16th of 256 ----
    {
        const int q = wave;
        float v = sm.a.top[q][lane >> 4][lane & 15];
#pragma unroll
        for (int k = 2; k <= 64; k <<= 1) {
#pragma unroll
            for (int j = k >> 1; j > 0; j >>= 1) {
                const float pv = __shfl_xor(v, j, 64);
                const bool keepMin = ((lane & j) == 0) == ((lane & k) == 0);
                v = keepMin ? fminf(v, pv) : fmaxf(v, pv);
            }
        }
        if (lane == 15) sm.a.tau[q] = v + SLACK;
    }
    __syncthreads();
    float tauS[4];
#pragma unroll
    for (int q = 0; q < 4; ++q) tauS[q] = sm.a.tau[q];

    // ---- Phase B: rescan, but only lanes that provably hold a candidate ----
    const bool anyc = (m1[0] <= tauS[0]) | (m1[1] <= tauS[1]) |
                      (m1[2] <= tauS[2]) | (m1[3] <= tauS[3]);
    if (anyc) {
#pragma unroll 4
        for (int j4 = 0; j4 < 8; ++j4) {
            const int ib = base + j4 * 256 + lane * 4;
            const float4 vx = *(const float4*)(px_ + ib);
            const float4 vy = *(const float4*)(py_ + ib);
            const float4 vz = *(const float4*)(pz_ + ib);
            float4 vp;
            if (PPQ) vp = *(const float4*)(ppb + ib);
            else vp = make_float4(sq3(vx.x, vy.x, vz.x), sq3(vx.y, vy.y, vz.y),
                                  sq3(vx.z, vy.z, vz.z), sq3(vx.w, vy.w, vz.w));
            const float pxa[4] = {vx.x, vx.y, vx.z, vx.w};
            const float pya[4] = {vy.x, vy.y, vy.z, vy.w};
            const float pza[4] = {vz.x, vz.y, vz.z, vz.w};
            const float ppa[4] = {vp.x, vp.y, vp.z, vp.w};
#pragma unroll
            for (int e = 0; e < 4; ++e) {
#pragma unroll
                for (int q = 0; q < 4; ++q) {
                    const float s = surr(nqx[q], nqy[q], nqz[q],
                                         pxa[e], pya[e], pza[e], ppa[e]);
                    if (s <= tauS[q]) {
                        const int pos = atomicAdd(&sm.a.cnt[q], 1);
                        if (pos < 64) sm.a.idx[q][pos] = ib + e;
                    }
                }
            }
        }
    }
    __syncthreads();

    // ---- Phase C: EXACT dist32 for candidates + bitonic sort (d, idx) ----
    {
        const int q = wave;
        const float qx = __fmul_rn(-0.5f, nqx[q]);
        const float qy = __fmul_rn(-0.5f, nqy[q]);
        const float qz = __fmul_rn(-0.5f, nqz[q]);
        const float qq = sq3(qx, qy, qz);
        const int cnt = min(sm.a.cnt[q], 64);
        float d = INF;
        int idx = 0x7fffffff;
        if (lane < cnt) {
            idx = sm.a.idx[q][lane];
            const float px = px_[idx], py = py_[idx], pz = pz_[idx];
            d = dist32(qx, qy, qz, qq, px, py, pz, sq3(px, py, pz));
        }
#pragma unroll
        for (int k = 2; k <= 64; k <<= 1) {
#pragma unroll
            for (int j = k >> 1; j > 0; j >>= 1) {
                const float pd = __shfl_xor(d, j, 64);
                const int   pi = __shfl_xor(idx, j, 64);
                const bool keepMin = ((lane & j) == 0) == ((lane & k) == 0);
                const bool pLess = (pd < d) || (pd == d && pi < idx);
                if (keepMin ? pLess : !pLess) { d = pd; idx = pi; }
            }
        }
        if (lane < KK) s_win[q][lane] = idx;
    }
    __syncthreads();   // s_win ready; sort buffers dead -> sm.g reuse OK

    const size_t chs = (size_t)MM * KK;
    float* ob = out + (size_t)b * (3 + CC) * chs + (size_t)m0 * KK + lane;

    if (PPQ) {
        // ---- stage 1: coalesced gather into LDS transpose buffer ----
        const float* ftb = feat + (size_t)b * NN * CC;   // fsN=64, fsC=1
        const int nb0 = wave * 16;
#pragma unroll
        for (int it = 0; it < 4; ++it) {
            const int nb = nb0 + it * 4 + (lane >> 4);   // 4 neighbors/instr
            const int cg = lane & 15;                    // 4 channels each
            const int idx = s_win[nb >> 4][nb & 15];
            const float4 v = *(const float4*)(ftb + (size_t)idx * CC + cg * 4);
            sm.g[3 + cg * 4 + 0][nb] = v.x;
            sm.g[3 + cg * 4 + 1][nb] = v.y;
            sm.g[3 + cg * 4 + 2][nb] = v.z;
            sm.g[3 + cg * 4 + 3][nb] = v.w;
        }
        if (lane < 16) {
            const int nb = nb0 + lane;
            const int q2 = nb >> 4;
            const int idx = s_win[q2][nb & 15];
            sm.g[0][nb] = __fsub_rn(px_[idx], __fmul_rn(-0.5f, nqx[q2]));
            sm.g[1][nb] = __fsub_rn(py_[idx], __fmul_rn(-0.5f, nqy[q2]));
            sm.g[2][nb] = __fsub_rn(pz_[idx], __fmul_rn(-0.5f, nqz[q2]));
        }
        __syncthreads();
        // ---- stage 2: conflict-free LDS reads + coalesced 256B stores ----
#pragma unroll
        for (int t = 0; t < 17; ++t) {
            const int c = wave + t * 4;
            if (c < 3 + CC) ob[(size_t)c * chs] = sm.g[c][lane];
        }
    } else {
        // Fallback (no ws): strided gather as before.
        const int q2 = lane >> 4;
        const int idx = s_win[q2][lane & 15];
        const float qxv = __fmul_rn(-0.5f, nqx[q2]);
        const float qyv = __fmul_rn(-0.5f, nqy[q2]);
        const float qzv = __fmul_rn(-0.5f, nqz[q2]);
        const float* fr = feat + (size_t)b * CC * NN + (size_t)idx * fsN;
#pragma unroll
        for (int t = 0; t < 17; ++t) {
            const int c = wave + t * 4;
            if (c < 3 + CC) {
                float val;
                if (c == 0)      val = __fsub_rn(px_[idx], qxv);
                else if (c == 1) val = __fsub_rn(py_[idx], qyv);
                else if (c == 2) val = __fsub_rn(pz_[idx], qzv);
                else             val = fr[(size_t)(c - 3) * fsC];
                ob[(size_t)c * chs] = val;
            }
        }
    }
}

extern "C" void kernel_launch(void* const* d_in, const int* in_sizes, int n_in,
                              void* d_out, int out_size, void* d_ws, size_t ws_size,
                              hipStream_t stream) {
    const float* points = (const float*)d_in[0];
    const float* newp   = (const float*)d_in[1];
    const float* feats  = (const float*)d_in[2];
    float* out = (float*)d_out;

    const size_t ftElems = (size_t)BB * NN * CC;
    const size_t needBytes = (ftElems + (size_t)BB * NN) * sizeof(float);
    if (ws_size >= needBytes) {
        float* ft  = (float*)d_ws;
        float* ppw = ft + ftElems;
        prep_feats_pp<<<dim3(NN / 64, BB), 256, 0, stream>>>(feats, points, ft, ppw);
        knn_group8<true><<<(BB * MM) / 4, 256, 0, stream>>>(points, newp, ft, CC, 1, ppw, out);
    } else {
        knn_group8<false><<<(BB * MM) / 4, 256, 0, stream>>>(points, newp, feats, 1, NN, nullptr, out);
    }
}